// Round 1
// 507.263 us; speedup vs baseline: 1.0070x; 1.0070x over previous
//
#include <hip/hip_runtime.h>
#include <math.h>

#define I_SZ   4096
#define H_SZ   3584
#define O_SZ   512
#define TOTAL  8192
#define HO     4096   // TOTAL - I_SZ (rows that actually update)
#define BETA   0.1f
#define LR     0.5f
#define T1C    20
#define T2C    4

#define NBLK   512    // persistent grid: 2 blocks/CU on 256 CUs
#define NTHR   512    // 8 waves -> 8 rows/block, 1 row/wave
#define NGRP   8      // barrier: 8 groups of 64 arrivals

// ---------------- init: state buffers + zero barrier state ----------------
__global__ void k_init(const float* __restrict__ x, float* __restrict__ s_a,
                       float* __restrict__ s_b, unsigned int* __restrict__ bar) {
    int i = blockIdx.x * 256 + threadIdx.x;
    if (i < I_SZ) { float v = x[i]; s_a[i] = v; s_b[i] = v; }
    else if (i < TOTAL) { s_a[i] = 0.0f; }
    if (i < 1024) bar[i] = 0u;
}

// ---------------- te[t] = mask*target; tsum = sum(te) ----------------
__global__ void k_prep(const float* __restrict__ target, const float* __restrict__ mask,
                       float* __restrict__ te, float* __restrict__ tsum) {
    __shared__ float red[8];
    int t = threadIdx.x;  // 512
    float v = mask[t] * target[t];
    te[t] = v;
    float z = v;
    for (int off = 32; off > 0; off >>= 1) z += __shfl_down(z, off, 64);
    if ((t & 63) == 0) red[t >> 6] = z;
    __syncthreads();
    if (t == 0) { float s = 0.f; for (int i = 0; i < 8; i++) s += red[i]; tsum[0] = s; }
}

// ---------------- build Wt = sym(W) lower-right block, 0.5 baked in ----------------
__global__ void k_build_wt(const float* __restrict__ W, float* __restrict__ Wt) {
    __shared__ float tb[32][33];
    int c0 = blockIdx.x * 32;
    int r0 = blockIdx.y * 32;
    int tx = threadIdx.x;   // 0..31
    int ty = threadIdx.y;   // 0..7
    #pragma unroll
    for (int k = 0; k < 4; k++) {
        int a = ty + 8 * k;
        tb[a][tx] = W[(size_t)(I_SZ + c0 + a) * TOTAL + (I_SZ + r0 + tx)];
    }
    __syncthreads();
    #pragma unroll
    for (int k = 0; k < 4; k++) {
        int ri = ty + 8 * k;
        int r = r0 + ri, c = c0 + tx;
        float direct = W[(size_t)(I_SZ + r) * TOTAL + (I_SZ + c)];
        Wt[(size_t)r * HO + c] = 0.5f * (direct + tb[tx][ri]);
    }
}

// ---------------- bvec[r] = 0.5 * W[I_SZ+r][0:I_SZ] . x (store) ----------------
__global__ void k_build_b1(const float* __restrict__ W, const float* __restrict__ x,
                           float* __restrict__ bvec) {
    int r = blockIdx.x;
    int t = threadIdx.x;
    const float4* wrow = (const float4*)(W + (size_t)(I_SZ + r) * TOTAL);
    const float4* xv   = (const float4*)x;
    float acc = 0.0f;
    #pragma unroll
    for (int k = 0; k < 4; k++) {
        int idx = t + 256 * k;       // < 1024
        float4 w  = wrow[idx];
        float4 s4 = xv[idx];
        acc += w.x * s4.x + w.y * s4.y + w.z * s4.z + w.w * s4.w;
    }
    __shared__ float red[4];
    for (int off = 32; off > 0; off >>= 1) acc += __shfl_down(acc, off, 64);
    if ((t & 63) == 0) red[t >> 6] = acc;
    __syncthreads();
    if (t == 0) bvec[r] = 0.5f * (red[0] + red[1] + red[2] + red[3]);
}

// ---------------- bvec[c] += 0.5 * sum_j W[j][I_SZ+c]*x[j] (atomic, after b1) --------
__global__ void k_build_b2(const float* __restrict__ W, const float* __restrict__ x,
                           float* __restrict__ bvec) {
    int c  = blockIdx.x * 256 + threadIdx.x;   // 0..HO-1
    int j0 = blockIdx.y * 64;
    float acc = 0.0f;
    for (int j = j0; j < j0 + 64; j++)
        acc += W[(size_t)j * TOTAL + (I_SZ + c)] * x[j];
    atomicAdd(&bvec[c], 0.5f * acc);
}

// ---------------- persistent kernel: all 24 steps, hand-rolled barrier ----------------
// bar layout (uints): cnt[g] at bar[g*64] (g=0..7), gcnt at bar[512], flag at bar[576]
//
// R(this): Wt row is loop-invariant -> load ONCE into 64 VGPRs/lane and hold
// across all 24 iterations. Eliminates 23/24 of the 1.5 GB Wt stream.
// __launch_bounds__(512,4) caps VGPRs at 128/lane; row (64) + body (~30) fits.
__global__ void __launch_bounds__(NTHR, 4) k_run(
    const float* __restrict__ Wt, const float* __restrict__ bvec,
    const float* __restrict__ te, const float* __restrict__ tsum,
    float* __restrict__ s_a, float* __restrict__ s_b,
    unsigned int* __restrict__ bar)
{
    const int blk  = blockIdx.x;
    const int tid  = threadIdx.x;
    const int wave = tid >> 6;
    const int lane = tid & 63;
    const int row  = blk * 8 + wave;          // 0..HO-1
    const float4* w4 = (const float4*)(Wt + (size_t)row * HO);
    const float   ts = tsum[0];
    const float   bv = bvec[row];
    const bool out_block = (blk >= H_SZ / 8); // blocks owning rows >= H_SZ

    __shared__ float sh[HO];                  // staged s_tail (16 KB)
    __shared__ float red[8];
    __shared__ float sm_m, sm_z;

    // ---- load this wave's Wt row ONCE; lives in VGPRs for all 24 steps ----
    float4 w[16];
    #pragma unroll
    for (int k = 0; k < 16; ++k) w[k] = w4[lane + 64 * k];

    for (int it = 0; it < T1C + T2C; ++it) {
        const float* cur = (it & 1) ? s_b : s_a;
        float*       nxt = (it & 1) ? s_a : s_b;
        const bool betap = (it >= T1C);

        // ---- stage s_tail -> LDS through the coherence point (agent-scope 8B loads)
        const unsigned long long* cu = (const unsigned long long*)(cur + I_SZ);
        unsigned long long* shu = (unsigned long long*)sh;
        #pragma unroll
        for (int m = 0; m < 4; ++m) {
            int idx = tid + NTHR * m;         // < 2048
            shu[idx] = __hip_atomic_load(&cu[idx], __ATOMIC_RELAXED,
                                         __HIP_MEMORY_SCOPE_AGENT);
        }
        __syncthreads();

        // ---- block-redundant softmax stats (beta phase, output-row blocks only)
        if (betap && out_block) {
            float l = sh[H_SZ + tid];         // logit j=tid
            float m = l;
            for (int off = 32; off > 0; off >>= 1) m = fmaxf(m, __shfl_down(m, off, 64));
            if (lane == 0) red[wave] = m;
            __syncthreads();
            if (tid == 0) { float v = red[0]; for (int i = 1; i < 8; i++) v = fmaxf(v, red[i]); sm_m = v; }
            __syncthreads();
            float z = expf(l - sm_m);
            for (int off = 32; off > 0; off >>= 1) z += __shfl_down(z, off, 64);
            if (lane == 0) red[wave] = z;
            __syncthreads();
            if (tid == 0) { float v = 0.f; for (int i = 0; i < 8; i++) v += red[i]; sm_z = v; }
            __syncthreads();
        }

        // ---- one wave per row: 4096-wide dot, Wt row held in registers, s from LDS
        const float4* sh4 = (const float4*)sh;
        float acc = 0.0f;
        #pragma unroll
        for (int k = 0; k < 16; ++k) {
            float4 s = sh4[lane + 64 * k];
            acc += w[k].x * s.x + w[k].y * s.y + w[k].z * s.z + w[k].w * s.w;
        }
        for (int off = 32; off > 0; off >>= 1) acc += __shfl_down(acc, off, 64);
        if (lane == 0) {
            float g = acc + bv;
            if (betap && row >= H_SZ) {
                float p = expf(sh[row] - sm_m) / sm_z;   // sh[row] == logit of this row
                g += -BETA * (p * ts - te[row - H_SZ]);
            }
            float nv = tanhf(sh[row] - LR * g);          // sh[row] == s_cur[I_SZ+row]
            __hip_atomic_store(&nxt[I_SZ + row], nv, __ATOMIC_RELAXED,
                               __HIP_MEMORY_SCOPE_AGENT);
        }
        __syncthreads();   // drains vmcnt: all agent stores complete at coherence point

        // ---- hierarchical monotone barrier (relaxed agent atomics, no cache flushes)
        const unsigned int e = (unsigned int)(it + 1);
        if (tid == 0) {
            unsigned int g = (unsigned int)blk >> 6;     // 0..7
            unsigned int v = __hip_atomic_fetch_add(&bar[g * 64], 1u, __ATOMIC_RELAXED,
                                                    __HIP_MEMORY_SCOPE_AGENT);
            if (v == e * 64u - 1u) {
                unsigned int v2 = __hip_atomic_fetch_add(&bar[512], 1u, __ATOMIC_RELAXED,
                                                         __HIP_MEMORY_SCOPE_AGENT);
                if (v2 == e * (unsigned int)NGRP - 1u)
                    __hip_atomic_store(&bar[576], e, __ATOMIC_RELAXED,
                                       __HIP_MEMORY_SCOPE_AGENT);
            }
            while (__hip_atomic_load(&bar[576], __ATOMIC_RELAXED,
                                     __HIP_MEMORY_SCOPE_AGENT) < e)
                __builtin_amdgcn_s_sleep(1);
        }
        __syncthreads();
    }
}

// ---------------- fallback per-step kernel (R5 structure) ----------------
template <bool BETA_STEP>
__global__ void __launch_bounds__(256, 4) k_step4(
    const float* __restrict__ Wt, const float* __restrict__ bvec,
    const float* __restrict__ s_cur, float* __restrict__ s_next,
    const float* __restrict__ te, const float* __restrict__ tsum)
{
    const int blk  = blockIdx.x;
    const int t    = threadIdx.x;
    const int wave = t >> 6;
    const int lane = t & 63;
    const int row  = blk * 4 + wave;

    __shared__ float red[4];
    __shared__ float sm_m, sm_z;

    if (BETA_STEP && blk >= H_SZ / 4) {
        float l0 = s_cur[I_SZ + H_SZ + t];
        float l1 = s_cur[I_SZ + H_SZ + t + 256];
        float m = fmaxf(l0, l1);
        for (int off = 32; off > 0; off >>= 1) m = fmaxf(m, __shfl_down(m, off, 64));
        if (lane == 0) red[wave] = m;
        __syncthreads();
        if (t == 0) sm_m = fmaxf(fmaxf(red[0], red[1]), fmaxf(red[2], red[3]));
        __syncthreads();
        float z = expf(l0 - sm_m) + expf(l1 - sm_m);
        for (int off = 32; off > 0; off >>= 1) z += __shfl_down(z, off, 64);
        if (lane == 0) red[wave] = z;
        __syncthreads();
        if (t == 0) sm_z = red[0] + red[1] + red[2] + red[3];
        __syncthreads();
    }

    const float4* w4 = (const float4*)(Wt + (size_t)row * HO);
    const float4* s4 = (const float4*)(s_cur + I_SZ);
    float4 w[16];
    #pragma unroll
    for (int k = 0; k < 16; k++) w[k] = w4[lane + 64 * k];
    float acc = 0.0f;
    #pragma unroll
    for (int k = 0; k < 16; k++) {
        float4 s = s4[lane + 64 * k];
        acc += w[k].x * s.x + w[k].y * s.y + w[k].z * s.z + w[k].w * s.w;
    }
    for (int off = 32; off > 0; off >>= 1) acc += __shfl_down(acc, off, 64);
    if (lane == 0) {
        float g = acc + bvec[row];
        if (BETA_STEP && row >= H_SZ) {
            int j = row - H_SZ;
            float p = expf(s_cur[I_SZ + H_SZ + j] - sm_m) / sm_z;
            g += -BETA * (p * tsum[0] - te[j]);
        }
        int i = I_SZ + row;
        s_next[i] = tanhf(s_cur[i] - LR * g);
    }
}

extern "C" void kernel_launch(void* const* d_in, const int* in_sizes, int n_in,
                              void* d_out, int out_size, void* d_ws, size_t ws_size,
                              hipStream_t stream) {
    const float* W      = (const float*)d_in[0];
    const float* x      = (const float*)d_in[1];
    const float* target = (const float*)d_in[2];
    const float* mask   = (const float*)d_in[3];
    float* out = (float*)d_out;   // state buffer A (24 steps even -> final lands here)
    char*  ws  = (char*)d_ws;

    const size_t WS_WT = (size_t)HO * HO * sizeof(float);   // 64 MB
    float*        Wt   = (float*)ws;
    float*        bvec = (float*)(ws + WS_WT);
    float*        te   = bvec + HO;
    float*        tsum = te + O_SZ;
    float*        s_b  = tsum + 64;
    unsigned int* bar  = (unsigned int*)(s_b + TOTAL + 64);

    k_init<<<(TOTAL + 255) / 256, 256, 0, stream>>>(x, out, s_b, bar);
    k_prep<<<1, 512, 0, stream>>>(target, mask, te, tsum);
    k_build_wt<<<dim3(HO / 32, HO / 32), dim3(32, 8), 0, stream>>>(W, Wt);
    k_build_b1<<<HO, 256, 0, stream>>>(W, x, bvec);
    k_build_b2<<<dim3(HO / 256, I_SZ / 64), 256, 0, stream>>>(W, x, bvec);

    void* args[] = { (void*)&Wt, (void*)&bvec, (void*)&te, (void*)&tsum,
                     (void*)&out, (void*)&s_b, (void*)&bar };
    hipError_t err = hipLaunchCooperativeKernel((const void*)k_run, dim3(NBLK), dim3(NTHR),
                                                args, 0, stream);
    if (err != hipSuccess) {
        // fallback: 24-dispatch chain (R5 structure, known-good 654 us)
        const float* cur = out;
        float* nxt = s_b;
        for (int it = 0; it < T1C + T2C; it++) {
            if (it >= T1C) {
                k_step4<true><<<HO / 4, 256, 0, stream>>>(Wt, bvec, cur, nxt, te, tsum);
            } else {
                k_step4<false><<<HO / 4, 256, 0, stream>>>(Wt, bvec, cur, nxt, te, tsum);
            }
            float* tmp = (float*)cur; cur = nxt; nxt = tmp;
        }
    }
}

// Round 2
// 496.230 us; speedup vs baseline: 1.0294x; 1.0222x over previous
//
#include <hip/hip_runtime.h>
#include <math.h>

#define I_SZ   4096
#define H_SZ   3584
#define O_SZ   512
#define TOTAL  8192
#define HO     4096   // TOTAL - I_SZ (rows that actually update)
#define BETA   0.1f
#define LR     0.5f
#define T1C    20
#define T2C    4

#define NBLK   256    // persistent grid: 1 block/CU on 256 CUs
#define NTHR   1024   // 16 waves -> 16 rows/block, 1 row/wave
#define GSH    5      // 32 blocks per barrier group
#define NGRP   8      // 8 groups

// ---------------- init: state buffers + zero barrier state ----------------
__global__ void k_init(const float* __restrict__ x, float* __restrict__ s_a,
                       float* __restrict__ s_b, unsigned int* __restrict__ bar) {
    int i = blockIdx.x * 256 + threadIdx.x;
    if (i < I_SZ) { float v = x[i]; s_a[i] = v; s_b[i] = v; }
    else if (i < TOTAL) { s_a[i] = 0.0f; }
    if (i < 1024) bar[i] = 0u;
}

// ---------------- te[t] = mask*target; tsum = sum(te) ----------------
__global__ void k_prep(const float* __restrict__ target, const float* __restrict__ mask,
                       float* __restrict__ te, float* __restrict__ tsum) {
    __shared__ float red[8];
    int t = threadIdx.x;  // 512
    float v = mask[t] * target[t];
    te[t] = v;
    float z = v;
    for (int off = 32; off > 0; off >>= 1) z += __shfl_down(z, off, 64);
    if ((t & 63) == 0) red[t >> 6] = z;
    __syncthreads();
    if (t == 0) { float s = 0.f; for (int i = 0; i < 8; i++) s += red[i]; tsum[0] = s; }
}

// ---------------- build Wt = sym(W) lower-right block, 0.5 baked in ----------------
// Triangle-pair scheme: block (bi,bj) with bi<=bj loads tiles (bi,bj) and (bj,bi)
// ONCE each and writes both symmetrized outputs -> halves read traffic vs R1.
__global__ void k_build_wt(const float* __restrict__ W, float* __restrict__ Wt) {
    int bj = blockIdx.x, bi = blockIdx.y;
    if (bi > bj) return;                      // upper-triangle pairs only
    __shared__ float ta[32][33], tb[32][33];
    int tx = threadIdx.x;   // 0..31
    int ty = threadIdx.y;   // 0..7
    int r0 = bi * 32, c0 = bj * 32;
    #pragma unroll
    for (int k = 0; k < 4; k++) {
        int a = ty + 8 * k;
        ta[a][tx] = W[(size_t)(I_SZ + r0 + a) * TOTAL + (I_SZ + c0 + tx)];
    }
    if (bi != bj) {
        #pragma unroll
        for (int k = 0; k < 4; k++) {
            int a = ty + 8 * k;
            tb[a][tx] = W[(size_t)(I_SZ + c0 + a) * TOTAL + (I_SZ + r0 + tx)];
        }
    }
    __syncthreads();
    if (bi == bj) {
        #pragma unroll
        for (int k = 0; k < 4; k++) {
            int a = ty + 8 * k;
            Wt[(size_t)(r0 + a) * HO + (c0 + tx)] = 0.5f * (ta[a][tx] + ta[tx][a]);
        }
    } else {
        #pragma unroll
        for (int k = 0; k < 4; k++) {
            int a = ty + 8 * k;
            // Wt[r][c] = 0.5*(W[I+r][I+c] + W[I+c][I+r])
            Wt[(size_t)(r0 + a) * HO + (c0 + tx)] = 0.5f * (ta[a][tx] + tb[tx][a]);
            Wt[(size_t)(c0 + a) * HO + (r0 + tx)] = 0.5f * (tb[a][tx] + ta[tx][a]);
        }
    }
}

// ---------------- bvec[r] = 0.5 * W[I_SZ+r][0:I_SZ] . x (store) ----------------
__global__ void k_build_b1(const float* __restrict__ W, const float* __restrict__ x,
                           float* __restrict__ bvec) {
    int r = blockIdx.x;
    int t = threadIdx.x;
    const float4* wrow = (const float4*)(W + (size_t)(I_SZ + r) * TOTAL);
    const float4* xv   = (const float4*)x;
    float acc = 0.0f;
    #pragma unroll
    for (int k = 0; k < 4; k++) {
        int idx = t + 256 * k;       // < 1024
        float4 w  = wrow[idx];
        float4 s4 = xv[idx];
        acc += w.x * s4.x + w.y * s4.y + w.z * s4.z + w.w * s4.w;
    }
    __shared__ float red[4];
    for (int off = 32; off > 0; off >>= 1) acc += __shfl_down(acc, off, 64);
    if ((t & 63) == 0) red[t >> 6] = acc;
    __syncthreads();
    if (t == 0) bvec[r] = 0.5f * (red[0] + red[1] + red[2] + red[3]);
}

// ---------------- bvec[c] += 0.5 * sum_j W[j][I_SZ+c]*x[j] (atomic, after b1) --------
__global__ void k_build_b2(const float* __restrict__ W, const float* __restrict__ x,
                           float* __restrict__ bvec) {
    int c  = blockIdx.x * 256 + threadIdx.x;   // 0..HO-1
    int j0 = blockIdx.y * 64;
    float acc = 0.0f;
    for (int j = j0; j < j0 + 64; j++)
        acc += W[(size_t)j * TOTAL + (I_SZ + c)] * x[j];
    atomicAdd(&bvec[c], 0.5f * acc);
}

// ---------------- persistent kernel: all 24 steps, hand-rolled barrier ----------------
// bar layout (uints): cnt[g] at bar[g*64] (g=0..7), gcnt at bar[512],
// per-group release flags at bar[576 + g*32] (one 128B line per group).
//
// R2 structure: 256 blocks x 16 waves (1 block/CU), 1 row/wave held in 64 VGPRs.
//  - barrier arrivals 512 -> 256; release via per-group flag lines (32 spinners/line)
//  - softmax stats computed wave-locally (butterfly shfl_xor) -> zero extra syncthreads
__global__ void __launch_bounds__(NTHR, 4) k_run(
    const float* __restrict__ Wt, const float* __restrict__ bvec,
    const float* __restrict__ te, const float* __restrict__ tsum,
    float* __restrict__ s_a, float* __restrict__ s_b,
    unsigned int* __restrict__ bar)
{
    const int blk  = blockIdx.x;
    const int tid  = threadIdx.x;
    const int wave = tid >> 6;
    const int lane = tid & 63;
    const int row  = blk * 16 + wave;         // 0..HO-1
    const float4* w4 = (const float4*)(Wt + (size_t)row * HO);
    const float   ts = tsum[0];
    const float   bv = bvec[row];
    const float   tev = (row >= H_SZ) ? te[row - H_SZ] : 0.0f;
    const bool out_block = (blk >= H_SZ / 16); // blocks owning rows >= H_SZ

    __shared__ float sh[HO];                  // staged s_tail (16 KB)

    // ---- load this wave's Wt row ONCE; lives in VGPRs for all 24 steps ----
    float4 w[16];
    #pragma unroll
    for (int k = 0; k < 16; ++k) w[k] = w4[lane + 64 * k];

    for (int it = 0; it < T1C + T2C; ++it) {
        const float* cur = (it & 1) ? s_b : s_a;
        float*       nxt = (it & 1) ? s_a : s_b;
        const bool betap = (it >= T1C);

        // ---- stage s_tail -> LDS through the coherence point (agent-scope 8B loads)
        const unsigned long long* cu = (const unsigned long long*)(cur + I_SZ);
        unsigned long long* shu = (unsigned long long*)sh;
        #pragma unroll
        for (int m = 0; m < 2; ++m) {
            int idx = tid + NTHR * m;         // < 2048
            shu[idx] = __hip_atomic_load(&cu[idx], __ATOMIC_RELAXED,
                                         __HIP_MEMORY_SCOPE_AGENT);
        }
        __syncthreads();

        const float4* sh4 = (const float4*)sh;

        // ---- wave-local redundant softmax stats (beta phase, output-row blocks only)
        // Each wave reduces all 512 logits itself: no cross-wave sync needed.
        float sm_m = 0.f, sm_z = 1.f;
        if (betap && out_block) {
            // conflict-free: stride 16B across lanes
            float4 l0 = sh4[H_SZ / 4 + lane];        // floats 3584+4l ..
            float4 l1 = sh4[H_SZ / 4 + 64 + lane];   // floats 3840+4l ..
            float m = fmaxf(fmaxf(fmaxf(l0.x, l0.y), fmaxf(l0.z, l0.w)),
                            fmaxf(fmaxf(l1.x, l1.y), fmaxf(l1.z, l1.w)));
            for (int off = 32; off > 0; off >>= 1) m = fmaxf(m, __shfl_xor(m, off, 64));
            float z = expf(l0.x - m) + expf(l0.y - m) + expf(l0.z - m) + expf(l0.w - m)
                    + expf(l1.x - m) + expf(l1.y - m) + expf(l1.z - m) + expf(l1.w - m);
            for (int off = 32; off > 0; off >>= 1) z += __shfl_xor(z, off, 64);
            sm_m = m; sm_z = z;
        }

        // ---- one wave per row: 4096-wide dot, Wt row held in registers, s from LDS
        float acc = 0.0f;
        #pragma unroll
        for (int k = 0; k < 16; ++k) {
            float4 s = sh4[lane + 64 * k];
            acc += w[k].x * s.x + w[k].y * s.y + w[k].z * s.z + w[k].w * s.w;
        }
        for (int off = 32; off > 0; off >>= 1) acc += __shfl_down(acc, off, 64);
        if (lane == 0) {
            float g = acc + bv;
            if (betap && row >= H_SZ) {
                float p = expf(sh[row] - sm_m) / sm_z;   // sh[row] == logit of this row
                g += -BETA * (p * ts - tev);
            }
            float nv = tanhf(sh[row] - LR * g);          // sh[row] == s_cur[I_SZ+row]
            __hip_atomic_store(&nxt[I_SZ + row], nv, __ATOMIC_RELAXED,
                               __HIP_MEMORY_SCOPE_AGENT);
        }
        __syncthreads();   // drains vmcnt: all agent stores complete at coherence point

        // ---- hierarchical monotone barrier (relaxed agent atomics, no cache flushes)
        const unsigned int e = (unsigned int)(it + 1);
        if (tid == 0) {
            unsigned int g = (unsigned int)blk >> GSH;   // 0..7
            unsigned int v = __hip_atomic_fetch_add(&bar[g * 64], 1u, __ATOMIC_RELAXED,
                                                    __HIP_MEMORY_SCOPE_AGENT);
            if (v == e * 32u - 1u) {
                unsigned int v2 = __hip_atomic_fetch_add(&bar[512], 1u, __ATOMIC_RELAXED,
                                                         __HIP_MEMORY_SCOPE_AGENT);
                if (v2 == e * (unsigned int)NGRP - 1u) {
                    #pragma unroll
                    for (int q = 0; q < NGRP; ++q)
                        __hip_atomic_store(&bar[576 + q * 32], e, __ATOMIC_RELAXED,
                                           __HIP_MEMORY_SCOPE_AGENT);
                }
            }
            while (__hip_atomic_load(&bar[576 + g * 32], __ATOMIC_RELAXED,
                                     __HIP_MEMORY_SCOPE_AGENT) < e)
                __builtin_amdgcn_s_sleep(1);
        }
        __syncthreads();
    }
}

// ---------------- fallback per-step kernel (R5 structure) ----------------
template <bool BETA_STEP>
__global__ void __launch_bounds__(256, 4) k_step4(
    const float* __restrict__ Wt, const float* __restrict__ bvec,
    const float* __restrict__ s_cur, float* __restrict__ s_next,
    const float* __restrict__ te, const float* __restrict__ tsum)
{
    const int blk  = blockIdx.x;
    const int t    = threadIdx.x;
    const int wave = t >> 6;
    const int lane = t & 63;
    const int row  = blk * 4 + wave;

    __shared__ float red[4];
    __shared__ float sm_m, sm_z;

    if (BETA_STEP && blk >= H_SZ / 4) {
        float l0 = s_cur[I_SZ + H_SZ + t];
        float l1 = s_cur[I_SZ + H_SZ + t + 256];
        float m = fmaxf(l0, l1);
        for (int off = 32; off > 0; off >>= 1) m = fmaxf(m, __shfl_down(m, off, 64));
        if (lane == 0) red[wave] = m;
        __syncthreads();
        if (t == 0) sm_m = fmaxf(fmaxf(red[0], red[1]), fmaxf(red[2], red[3]));
        __syncthreads();
        float z = expf(l0 - sm_m) + expf(l1 - sm_m);
        for (int off = 32; off > 0; off >>= 1) z += __shfl_down(z, off, 64);
        if (lane == 0) red[wave] = z;
        __syncthreads();
        if (t == 0) sm_z = red[0] + red[1] + red[2] + red[3];
        __syncthreads();
    }

    const float4* w4 = (const float4*)(Wt + (size_t)row * HO);
    const float4* s4 = (const float4*)(s_cur + I_SZ);
    float4 w[16];
    #pragma unroll
    for (int k = 0; k < 16; k++) w[k] = w4[lane + 64 * k];
    float acc = 0.0f;
    #pragma unroll
    for (int k = 0; k < 16; k++) {
        float4 s = s4[lane + 64 * k];
        acc += w[k].x * s.x + w[k].y * s.y + w[k].z * s.z + w[k].w * s.w;
    }
    for (int off = 32; off > 0; off >>= 1) acc += __shfl_down(acc, off, 64);
    if (lane == 0) {
        float g = acc + bvec[row];
        if (BETA_STEP && row >= H_SZ) {
            int j = row - H_SZ;
            float p = expf(s_cur[I_SZ + H_SZ + j] - sm_m) / sm_z;
            g += -BETA * (p * tsum[0] - te[j]);
        }
        int i = I_SZ + row;
        s_next[i] = tanhf(s_cur[i] - LR * g);
    }
}

extern "C" void kernel_launch(void* const* d_in, const int* in_sizes, int n_in,
                              void* d_out, int out_size, void* d_ws, size_t ws_size,
                              hipStream_t stream) {
    const float* W      = (const float*)d_in[0];
    const float* x      = (const float*)d_in[1];
    const float* target = (const float*)d_in[2];
    const float* mask   = (const float*)d_in[3];
    float* out = (float*)d_out;   // state buffer A (24 steps even -> final lands here)
    char*  ws  = (char*)d_ws;

    const size_t WS_WT = (size_t)HO * HO * sizeof(float);   // 64 MB
    float*        Wt   = (float*)ws;
    float*        bvec = (float*)(ws + WS_WT);
    float*        te   = bvec + HO;
    float*        tsum = te + O_SZ;
    float*        s_b  = tsum + 64;
    unsigned int* bar  = (unsigned int*)(s_b + TOTAL + 64);

    k_init<<<(TOTAL + 255) / 256, 256, 0, stream>>>(x, out, s_b, bar);
    k_prep<<<1, 512, 0, stream>>>(target, mask, te, tsum);
    k_build_wt<<<dim3(HO / 32, HO / 32), dim3(32, 8), 0, stream>>>(W, Wt);
    k_build_b1<<<HO, 256, 0, stream>>>(W, x, bvec);
    k_build_b2<<<dim3(HO / 256, I_SZ / 64), 256, 0, stream>>>(W, x, bvec);

    void* args[] = { (void*)&Wt, (void*)&bvec, (void*)&te, (void*)&tsum,
                     (void*)&out, (void*)&s_b, (void*)&bar };
    hipError_t err = hipLaunchCooperativeKernel((const void*)k_run, dim3(NBLK), dim3(NTHR),
                                                args, 0, stream);
    if (err != hipSuccess) {
        // fallback: 24-dispatch chain (R5 structure, known-good 654 us)
        const float* cur = out;
        float* nxt = s_b;
        for (int it = 0; it < T1C + T2C; it++) {
            if (it >= T1C) {
                k_step4<true><<<HO / 4, 256, 0, stream>>>(Wt, bvec, cur, nxt, te, tsum);
            } else {
                k_step4<false><<<HO / 4, 256, 0, stream>>>(Wt, bvec, cur, nxt, te, tsum);
            }
            float* tmp = (float*)cur; cur = nxt; nxt = tmp;
        }
    }
}

// Round 3
// 486.486 us; speedup vs baseline: 1.0500x; 1.0200x over previous
//
#include <hip/hip_runtime.h>
#include <math.h>

#define I_SZ   4096
#define H_SZ   3584
#define O_SZ   512
#define TOTAL  8192
#define HO     4096   // TOTAL - I_SZ (rows that actually update)
#define BETA   0.1f
#define LR     0.5f
#define T1C    20
#define T2C    4

#define NBLK   256    // persistent grid: 1 block/CU on 256 CUs
#define NTHR   1024   // 16 waves -> 16 rows/block, 1 row/wave
#define GSH    5      // 32 blocks per barrier group
#define NGRP   8      // 8 groups

// fused setup role ranges (blockIdx.x), 256 threads/block
#define NB_WT   16384                 // 128x128 tile grid, triangle early-exit
#define NB_B1   4096                  // one block per row
#define NB_INIT 32                    // 32*256 = 8192 state elems
#define NB_ALL  (NB_WT + NB_B1 + NB_INIT + 1)   // +1 prep block

// ---------------- fused setup: build_wt + b1 + init + prep in ONE dispatch ----------
// Roles are independent (disjoint outputs); b2 (atomics into bvec) must wait for
// b1's stores -> separate dispatch after this one (stream order).
__global__ void k_setup1(const float* __restrict__ W, const float* __restrict__ x,
                         const float* __restrict__ target, const float* __restrict__ mask,
                         float* __restrict__ Wt, float* __restrict__ bvec,
                         float* __restrict__ te, float* __restrict__ tsum,
                         float* __restrict__ s_a, float* __restrict__ s_b,
                         unsigned int* __restrict__ bar)
{
    __shared__ float ta[32][33], tb[32][33];
    __shared__ float red[8];
    const int b = blockIdx.x;

    if (b < NB_WT) {
        // ---- build Wt = sym(W) lower-right block, 0.5 baked in (triangle-pair) ----
        int bj = b & 127, bi = b >> 7;
        if (bi > bj) return;                  // block-uniform early exit
        int tx = threadIdx.x & 31;            // 0..31
        int ty = threadIdx.x >> 5;            // 0..7
        int r0 = bi * 32, c0 = bj * 32;
        #pragma unroll
        for (int k = 0; k < 4; k++) {
            int a = ty + 8 * k;
            ta[a][tx] = W[(size_t)(I_SZ + r0 + a) * TOTAL + (I_SZ + c0 + tx)];
        }
        if (bi != bj) {
            #pragma unroll
            for (int k = 0; k < 4; k++) {
                int a = ty + 8 * k;
                tb[a][tx] = W[(size_t)(I_SZ + c0 + a) * TOTAL + (I_SZ + r0 + tx)];
            }
        }
        __syncthreads();
        if (bi == bj) {
            #pragma unroll
            for (int k = 0; k < 4; k++) {
                int a = ty + 8 * k;
                Wt[(size_t)(r0 + a) * HO + (c0 + tx)] = 0.5f * (ta[a][tx] + ta[tx][a]);
            }
        } else {
            #pragma unroll
            for (int k = 0; k < 4; k++) {
                int a = ty + 8 * k;
                Wt[(size_t)(r0 + a) * HO + (c0 + tx)] = 0.5f * (ta[a][tx] + tb[tx][a]);
                Wt[(size_t)(c0 + a) * HO + (r0 + tx)] = 0.5f * (tb[a][tx] + ta[tx][a]);
            }
        }
    } else if (b < NB_WT + NB_B1) {
        // ---- bvec[r] = 0.5 * W[I_SZ+r][0:I_SZ] . x (store) ----
        int r = b - NB_WT;
        int t = threadIdx.x;
        const float4* wrow = (const float4*)(W + (size_t)(I_SZ + r) * TOTAL);
        const float4* xv   = (const float4*)x;
        float acc = 0.0f;
        #pragma unroll
        for (int k = 0; k < 4; k++) {
            int idx = t + 256 * k;            // < 1024
            float4 w  = wrow[idx];
            float4 s4 = xv[idx];
            acc += w.x * s4.x + w.y * s4.y + w.z * s4.z + w.w * s4.w;
        }
        for (int off = 32; off > 0; off >>= 1) acc += __shfl_down(acc, off, 64);
        if ((t & 63) == 0) red[t >> 6] = acc;
        __syncthreads();
        if (t == 0) bvec[r] = 0.5f * (red[0] + red[1] + red[2] + red[3]);
    } else if (b < NB_WT + NB_B1 + NB_INIT) {
        // ---- init state buffers + zero barrier state ----
        int i = (b - NB_WT - NB_B1) * 256 + threadIdx.x;
        if (i < I_SZ) { float v = x[i]; s_a[i] = v; s_b[i] = v; }
        else if (i < TOTAL) { s_a[i] = 0.0f; }
        if (i < 1024) bar[i] = 0u;
    } else {
        // ---- te[t] = mask*target; tsum = sum(te) (one block, 2 elems/thread) ----
        int t = threadIdx.x;                  // 0..255
        float v0 = mask[t] * target[t];
        float v1 = mask[t + 256] * target[t + 256];
        te[t] = v0;
        te[t + 256] = v1;
        float z = v0 + v1;
        for (int off = 32; off > 0; off >>= 1) z += __shfl_down(z, off, 64);
        if ((t & 63) == 0) red[t >> 6] = z;
        __syncthreads();
        if (t == 0) tsum[0] = red[0] + red[1] + red[2] + red[3];
    }
}

// ---------------- bvec[c] += 0.5 * sum_j W[j][I_SZ+c]*x[j] (atomic, after b1) --------
__global__ void k_build_b2(const float* __restrict__ W, const float* __restrict__ x,
                           float* __restrict__ bvec) {
    int c  = blockIdx.x * 256 + threadIdx.x;   // 0..HO-1
    int j0 = blockIdx.y * 64;
    float acc = 0.0f;
    for (int j = j0; j < j0 + 64; j++)
        acc += W[(size_t)j * TOTAL + (I_SZ + c)] * x[j];
    atomicAdd(&bvec[c], 0.5f * acc);
}

// ---------------- persistent kernel: all 24 steps, hand-rolled barrier ----------------
// bar layout (uints): cnt[g] at bar[g*64] (g=0..7), gcnt at bar[512],
// per-group release flags at bar[576 + g*32] (one 128B line per group).
//
// 256 blocks x 16 waves (1 block/CU), 1 row/wave, Wt row held in 64 VGPRs.
// Softmax stats wave-local (butterfly shfl_xor). Final iteration skips the
// grid barrier entirely (no consumer inside the kernel).
__global__ void __launch_bounds__(NTHR, 4) k_run(
    const float* __restrict__ Wt, const float* __restrict__ bvec,
    const float* __restrict__ te, const float* __restrict__ tsum,
    float* __restrict__ s_a, float* __restrict__ s_b,
    unsigned int* __restrict__ bar)
{
    const int blk  = blockIdx.x;
    const int tid  = threadIdx.x;
    const int wave = tid >> 6;
    const int lane = tid & 63;
    const int row  = blk * 16 + wave;         // 0..HO-1
    const float4* w4 = (const float4*)(Wt + (size_t)row * HO);
    const float   ts = tsum[0];
    const float   bv = bvec[row];
    const float   tev = (row >= H_SZ) ? te[row - H_SZ] : 0.0f;
    const bool out_block = (blk >= H_SZ / 16); // blocks owning rows >= H_SZ

    __shared__ float sh[HO];                  // staged s_tail (16 KB)

    // ---- load this wave's Wt row ONCE; lives in VGPRs for all 24 steps ----
    float4 w[16];
    #pragma unroll
    for (int k = 0; k < 16; ++k) w[k] = w4[lane + 64 * k];

    for (int it = 0; it < T1C + T2C; ++it) {
        const float* cur = (it & 1) ? s_b : s_a;
        float*       nxt = (it & 1) ? s_a : s_b;
        const bool betap = (it >= T1C);

        // ---- stage s_tail -> LDS through the coherence point (agent-scope 8B loads)
        const unsigned long long* cu = (const unsigned long long*)(cur + I_SZ);
        unsigned long long* shu = (unsigned long long*)sh;
        #pragma unroll
        for (int m = 0; m < 2; ++m) {
            int idx = tid + NTHR * m;         // < 2048
            shu[idx] = __hip_atomic_load(&cu[idx], __ATOMIC_RELAXED,
                                         __HIP_MEMORY_SCOPE_AGENT);
        }
        __syncthreads();

        const float4* sh4 = (const float4*)sh;

        // ---- wave-local redundant softmax stats (beta phase, output-row blocks only)
        float sm_m = 0.f, sm_z = 1.f;
        if (betap && out_block) {
            float4 l0 = sh4[H_SZ / 4 + lane];        // floats 3584+4l ..
            float4 l1 = sh4[H_SZ / 4 + 64 + lane];   // floats 3840+4l ..
            float m = fmaxf(fmaxf(fmaxf(l0.x, l0.y), fmaxf(l0.z, l0.w)),
                            fmaxf(fmaxf(l1.x, l1.y), fmaxf(l1.z, l1.w)));
            for (int off = 32; off > 0; off >>= 1) m = fmaxf(m, __shfl_xor(m, off, 64));
            float z = expf(l0.x - m) + expf(l0.y - m) + expf(l0.z - m) + expf(l0.w - m)
                    + expf(l1.x - m) + expf(l1.y - m) + expf(l1.z - m) + expf(l1.w - m);
            for (int off = 32; off > 0; off >>= 1) z += __shfl_xor(z, off, 64);
            sm_m = m; sm_z = z;
        }

        // ---- one wave per row: 4096-wide dot, Wt row held in registers, s from LDS
        float acc = 0.0f;
        #pragma unroll
        for (int k = 0; k < 16; ++k) {
            float4 s = sh4[lane + 64 * k];
            acc += w[k].x * s.x + w[k].y * s.y + w[k].z * s.z + w[k].w * s.w;
        }
        for (int off = 32; off > 0; off >>= 1) acc += __shfl_down(acc, off, 64);
        if (lane == 0) {
            float g = acc + bv;
            if (betap && row >= H_SZ) {
                float p = expf(sh[row] - sm_m) / sm_z;   // sh[row] == logit of this row
                g += -BETA * (p * ts - tev);
            }
            float nv = tanhf(sh[row] - LR * g);          // sh[row] == s_cur[I_SZ+row]
            __hip_atomic_store(&nxt[I_SZ + row], nv, __ATOMIC_RELAXED,
                               __HIP_MEMORY_SCOPE_AGENT);
        }

        // ---- last iteration: stores drain at kernel end; no consumer inside ----
        if (it == T1C + T2C - 1) break;

        __syncthreads();   // drains vmcnt: all agent stores complete at coherence point

        // ---- hierarchical monotone barrier (relaxed agent atomics, no cache flushes)
        const unsigned int e = (unsigned int)(it + 1);
        if (tid == 0) {
            unsigned int g = (unsigned int)blk >> GSH;   // 0..7
            unsigned int v = __hip_atomic_fetch_add(&bar[g * 64], 1u, __ATOMIC_RELAXED,
                                                    __HIP_MEMORY_SCOPE_AGENT);
            if (v == e * 32u - 1u) {
                unsigned int v2 = __hip_atomic_fetch_add(&bar[512], 1u, __ATOMIC_RELAXED,
                                                         __HIP_MEMORY_SCOPE_AGENT);
                if (v2 == e * (unsigned int)NGRP - 1u) {
                    #pragma unroll
                    for (int q = 0; q < NGRP; ++q)
                        __hip_atomic_store(&bar[576 + q * 32], e, __ATOMIC_RELAXED,
                                           __HIP_MEMORY_SCOPE_AGENT);
                }
            }
            while (__hip_atomic_load(&bar[576 + g * 32], __ATOMIC_RELAXED,
                                     __HIP_MEMORY_SCOPE_AGENT) < e)
                __builtin_amdgcn_s_sleep(1);
        }
        __syncthreads();
    }
}

// ---------------- fallback per-step kernel (R5 structure) ----------------
template <bool BETA_STEP>
__global__ void __launch_bounds__(256, 4) k_step4(
    const float* __restrict__ Wt, const float* __restrict__ bvec,
    const float* __restrict__ s_cur, float* __restrict__ s_next,
    const float* __restrict__ te, const float* __restrict__ tsum)
{
    const int blk  = blockIdx.x;
    const int t    = threadIdx.x;
    const int wave = t >> 6;
    const int lane = t & 63;
    const int row  = blk * 4 + wave;

    __shared__ float red[4];
    __shared__ float sm_m, sm_z;

    if (BETA_STEP && blk >= H_SZ / 4) {
        float l0 = s_cur[I_SZ + H_SZ + t];
        float l1 = s_cur[I_SZ + H_SZ + t + 256];
        float m = fmaxf(l0, l1);
        for (int off = 32; off > 0; off >>= 1) m = fmaxf(m, __shfl_down(m, off, 64));
        if (lane == 0) red[wave] = m;
        __syncthreads();
        if (t == 0) sm_m = fmaxf(fmaxf(red[0], red[1]), fmaxf(red[2], red[3]));
        __syncthreads();
        float z = expf(l0 - sm_m) + expf(l1 - sm_m);
        for (int off = 32; off > 0; off >>= 1) z += __shfl_down(z, off, 64);
        if (lane == 0) red[wave] = z;
        __syncthreads();
        if (t == 0) sm_z = red[0] + red[1] + red[2] + red[3];
        __syncthreads();
    }

    const float4* w4 = (const float4*)(Wt + (size_t)row * HO);
    const float4* s4 = (const float4*)(s_cur + I_SZ);
    float4 w[16];
    #pragma unroll
    for (int k = 0; k < 16; k++) w[k] = w4[lane + 64 * k];
    float acc = 0.0f;
    #pragma unroll
    for (int k = 0; k < 16; k++) {
        float4 s = s4[lane + 64 * k];
        acc += w[k].x * s.x + w[k].y * s.y + w[k].z * s.z + w[k].w * s.w;
    }
    for (int off = 32; off > 0; off >>= 1) acc += __shfl_down(acc, off, 64);
    if (lane == 0) {
        float g = acc + bvec[row];
        if (BETA_STEP && row >= H_SZ) {
            int j = row - H_SZ;
            float p = expf(s_cur[I_SZ + H_SZ + j] - sm_m) / sm_z;
            g += -BETA * (p * tsum[0] - te[j]);
        }
        int i = I_SZ + row;
        s_next[i] = tanhf(s_cur[i] - LR * g);
    }
}

extern "C" void kernel_launch(void* const* d_in, const int* in_sizes, int n_in,
                              void* d_out, int out_size, void* d_ws, size_t ws_size,
                              hipStream_t stream) {
    const float* W      = (const float*)d_in[0];
    const float* x      = (const float*)d_in[1];
    const float* target = (const float*)d_in[2];
    const float* mask   = (const float*)d_in[3];
    float* out = (float*)d_out;   // state buffer A (24 steps even -> final lands here)
    char*  ws  = (char*)d_ws;

    const size_t WS_WT = (size_t)HO * HO * sizeof(float);   // 64 MB
    float*        Wt   = (float*)ws;
    float*        bvec = (float*)(ws + WS_WT);
    float*        te   = bvec + HO;
    float*        tsum = te + O_SZ;
    float*        s_b  = tsum + 64;
    unsigned int* bar  = (unsigned int*)(s_b + TOTAL + 64);

    k_setup1<<<NB_ALL, 256, 0, stream>>>(W, x, target, mask, Wt, bvec, te, tsum,
                                         out, s_b, bar);
    k_build_b2<<<dim3(HO / 256, I_SZ / 64), 256, 0, stream>>>(W, x, bvec);

    void* args[] = { (void*)&Wt, (void*)&bvec, (void*)&te, (void*)&tsum,
                     (void*)&out, (void*)&s_b, (void*)&bar };
    hipError_t err = hipLaunchCooperativeKernel((const void*)k_run, dim3(NBLK), dim3(NTHR),
                                                args, 0, stream);
    if (err != hipSuccess) {
        // fallback: 24-dispatch chain (R5 structure, known-good)
        const float* cur = out;
        float* nxt = s_b;
        for (int it = 0; it < T1C + T2C; it++) {
            if (it >= T1C) {
                k_step4<true><<<HO / 4, 256, 0, stream>>>(Wt, bvec, cur, nxt, te, tsum);
            } else {
                k_step4<false><<<HO / 4, 256, 0, stream>>>(Wt, bvec, cur, nxt, te, tsum);
            }
            float* tmp = (float*)cur; cur = nxt; nxt = tmp;
        }
    }
}